// Round 4
// baseline (199.596 us; speedup 1.0000x reference)
//
#include <hip/hip_runtime.h>
#include <math.h>

#define B_   128
#define T_   50
#define MI_  32
#define E_   128
#define EW_  16
#define D_   144
#define G_   432        // 3*D
#define N_   (B_*T_)    // 6400

// ---------------------------------------------------------------------------
// K1: basket embedding v2 — parallel gather (unchanged, known good).
// ---------------------------------------------------------------------------
__global__ __launch_bounds__(256) void embed_kernel(
    const int* __restrict__ x,            // [N_][33]
    const float* __restrict__ encode_w,   // [100000][128]  (row 0 == 0)
    const float* __restrict__ wchange_w,  // [2][16]
    float* __restrict__ seq)              // [N_][144]
{
    int n = blockIdx.x;
    int tid = threadIdx.x;
    int i = tid >> 3;        // item 0..31
    int j = tid & 7;         // col chunk [16j, 16j+16)

    __shared__ int xi[33];
    __shared__ __align__(16) float part[32 * 132];  // stride 132 words
    __shared__ float cntf[32];

    if (tid < 33) xi[tid] = x[n * 33 + tid];
    __syncthreads();

    int it = xi[i];
    const float* row = &encode_w[(size_t)it * E_];
    float4 v0 = *(const float4*)&row[16 * j + 0];
    float4 v1 = *(const float4*)&row[16 * j + 4];
    float4 v2 = *(const float4*)&row[16 * j + 8];
    float4 v3 = *(const float4*)&row[16 * j + 12];

    float* p = &part[i * 132 + 16 * j];
    *(float4*)&p[0]  = v0;
    *(float4*)&p[4]  = v1;
    *(float4*)&p[8]  = v2;
    *(float4*)&p[12] = v3;
    if (j == 0) cntf[i] = (it != 0) ? 1.f : 0.f;
    __syncthreads();

    if (tid < E_) {
        int c = tid;
        float s = 0.f, cn = 0.f;
        #pragma unroll
        for (int k = 0; k < 32; ++k) {
            s  += part[k * 132 + c];   // 2-way bank aliasing: free
            cn += cntf[k];             // broadcast: free
        }
        seq[n * D_ + c] = s / fmaxf(cn, 1.f);
    } else if (tid < E_ + EW_) {
        int c = tid - E_;
        seq[n * D_ + E_ + c] = wchange_w[xi[32] * EW_ + c];
    }
}

// ---------------------------------------------------------------------------
// K4 (small-N): C[M][N] = A[M][144] * Bw[N][144]^T + bias.  64x64 tile,
// 4x4 acc (unchanged — fine for N=128 where grid must stay >=200 blocks).
// ---------------------------------------------------------------------------
#define GK   144
#define GBK  48
#define GPAD 68

__global__ __launch_bounds__(256) void gemm_bias_kernel(
    const float* __restrict__ A,
    const float* __restrict__ Bw,
    const float* __restrict__ bias,
    float* __restrict__ C,
    int M, int N)
{
    __shared__ float As[GBK * GPAD];
    __shared__ float Bs[GBK * GPAD];

    int tid = threadIdx.x;
    int row0 = blockIdx.x * 64;
    int col0 = blockIdx.y * 64;
    int tx = tid & 15;        // col group
    int ty = tid >> 4;        // row group

    float acc[4][4] = {};

    int sr = tid >> 2;
    int skq0 = tid & 3;

    for (int k0 = 0; k0 < GK; k0 += GBK) {
        __syncthreads();
        #pragma unroll
        for (int i = 0; i < 3; ++i) {
            int kq = skq0 + i * 4;          // 0..11  (48 k / 4)
            float4 a = *(const float4*)&A[(size_t)(row0 + sr) * GK + k0 + kq * 4];
            int nrow = col0 + sr;
            float4 b = make_float4(0.f, 0.f, 0.f, 0.f);
            if (nrow < N)
                b = *(const float4*)&Bw[(size_t)nrow * GK + k0 + kq * 4];
            As[(kq * 4 + 0) * GPAD + sr] = a.x;
            As[(kq * 4 + 1) * GPAD + sr] = a.y;
            As[(kq * 4 + 2) * GPAD + sr] = a.z;
            As[(kq * 4 + 3) * GPAD + sr] = a.w;
            Bs[(kq * 4 + 0) * GPAD + sr] = b.x;
            Bs[(kq * 4 + 1) * GPAD + sr] = b.y;
            Bs[(kq * 4 + 2) * GPAD + sr] = b.z;
            Bs[(kq * 4 + 3) * GPAD + sr] = b.w;
        }
        __syncthreads();

        #pragma unroll 4
        for (int k = 0; k < GBK; ++k) {
            float4 a4 = *(const float4*)&As[k * GPAD + ty * 4];
            float4 b4 = *(const float4*)&Bs[k * GPAD + tx * 4];
            float av[4] = {a4.x, a4.y, a4.z, a4.w};
            float bv[4] = {b4.x, b4.y, b4.z, b4.w};
            #pragma unroll
            for (int i = 0; i < 4; ++i)
                #pragma unroll
                for (int j = 0; j < 4; ++j)
                    acc[i][j] = fmaf(av[i], bv[j], acc[i][j]);
        }
    }

    int c = col0 + tx * 4;
    if (c < N) {
        float4 bb = *(const float4*)&bias[c];
        #pragma unroll
        for (int i = 0; i < 4; ++i) {
            int r = row0 + ty * 4 + i;
            float4 o;
            o.x = acc[i][0] + bb.x;
            o.y = acc[i][1] + bb.y;
            o.z = acc[i][2] + bb.z;
            o.w = acc[i][3] + bb.w;
            *(float4*)&C[(size_t)r * N + c] = o;
        }
    }
}

// ---------------------------------------------------------------------------
// K2 (big-N): 128x128 tile, 8x8 acc per thread.  Theory: the 64x64/4x4
// kernel issues 2 ds_read_b128 per 16 FMA -> 1 b128 per 4 cyc per CU demand
// vs ~1 per 8-12 cyc LDS capacity (m134): 3x over-subscribed, ~20% of peak.
// 8x8 halves LDS demand per FLOP (4 b128 per 64 FMA -> 1 per 8 cyc), and the
// lane mapping (wave covers tx,ty in 0..7) makes both A and B fragment reads
// 8 distinct 32B addresses = 2-way bank alias = free (m136).
// ---------------------------------------------------------------------------
#define K2P 132   // padded LDS row stride (floats)

__global__ __launch_bounds__(256) void gemm128_bias_kernel(
    const float* __restrict__ A,    // [M][144]
    const float* __restrict__ Bw,   // [N][144]
    const float* __restrict__ bias, // [N]
    float* __restrict__ C,          // [M][N]
    int M, int N)
{
    __shared__ __align__(16) float As[GBK * K2P];
    __shared__ __align__(16) float Bs[GBK * K2P];

    int tid = threadIdx.x;
    int row0 = blockIdx.x * 128;
    int col0 = blockIdx.y * 128;

    // 16x16 thread grid; each WAVE covers tx,ty in 0..7 (bank-friendly)
    int tx = (tid & 7) | (((tid >> 6) & 1) << 3);
    int ty = ((tid >> 3) & 7) | (((tid >> 7) & 1) << 3);

    int srow = tid & 127;          // staged row/col
    int sq0  = (tid >> 7) * 6;     // f4-chunk base (0 or 6)

    float acc[8][8] = {};

    for (int k0 = 0; k0 < GK; k0 += GBK) {
        __syncthreads();
        #pragma unroll
        for (int i = 0; i < 6; ++i) {
            int q = sq0 + i;       // 0..11 covers 48 k as 12 float4
            float4 a = *(const float4*)&A[(size_t)(row0 + srow) * GK + k0 + q * 4];
            float4 b = make_float4(0.f, 0.f, 0.f, 0.f);
            int nrow = col0 + srow;
            if (nrow < N)
                b = *(const float4*)&Bw[(size_t)nrow * GK + k0 + q * 4];
            As[(q * 4 + 0) * K2P + srow] = a.x;
            As[(q * 4 + 1) * K2P + srow] = a.y;
            As[(q * 4 + 2) * K2P + srow] = a.z;
            As[(q * 4 + 3) * K2P + srow] = a.w;
            Bs[(q * 4 + 0) * K2P + srow] = b.x;
            Bs[(q * 4 + 1) * K2P + srow] = b.y;
            Bs[(q * 4 + 2) * K2P + srow] = b.z;
            Bs[(q * 4 + 3) * K2P + srow] = b.w;
        }
        __syncthreads();

        #pragma unroll 4
        for (int k = 0; k < GBK; ++k) {
            float4 a0 = *(const float4*)&As[k * K2P + ty * 8];
            float4 a1 = *(const float4*)&As[k * K2P + ty * 8 + 4];
            float4 b0 = *(const float4*)&Bs[k * K2P + tx * 8];
            float4 b1 = *(const float4*)&Bs[k * K2P + tx * 8 + 4];
            float av[8] = {a0.x, a0.y, a0.z, a0.w, a1.x, a1.y, a1.z, a1.w};
            float bv[8] = {b0.x, b0.y, b0.z, b0.w, b1.x, b1.y, b1.z, b1.w};
            #pragma unroll
            for (int i = 0; i < 8; ++i)
                #pragma unroll
                for (int j = 0; j < 8; ++j)
                    acc[i][j] = fmaf(av[i], bv[j], acc[i][j]);
        }
    }

    int c0 = col0 + tx * 8;
    bool v0 = (c0 < N), v1 = (c0 + 4 < N);
    float4 bb0 = v0 ? *(const float4*)&bias[c0]     : make_float4(0.f,0.f,0.f,0.f);
    float4 bb1 = v1 ? *(const float4*)&bias[c0 + 4] : make_float4(0.f,0.f,0.f,0.f);
    #pragma unroll
    for (int i = 0; i < 8; ++i) {
        int r = row0 + ty * 8 + i;
        if (v0) {
            float4 o;
            o.x = acc[i][0] + bb0.x;
            o.y = acc[i][1] + bb0.y;
            o.z = acc[i][2] + bb0.z;
            o.w = acc[i][3] + bb0.w;
            *(float4*)&C[(size_t)r * N + c0] = o;
        }
        if (v1) {
            float4 o;
            o.x = acc[i][4] + bb1.x;
            o.y = acc[i][5] + bb1.y;
            o.z = acc[i][6] + bb1.z;
            o.w = acc[i][7] + bb1.w;
            *(float4*)&C[(size_t)r * N + c0 + 4] = o;
        }
    }
}

// ---------------------------------------------------------------------------
// K3: GRU v7 = v6 + no-vmem-drain barriers.  __syncthreads forces
// s_waitcnt vmcnt(0) (m97 asm evidence), so bar2 stalled ~300-500cyc on the
// hseq STORE every step and bar1 on the gi prefetch drain.  Neither drain is
// needed: no cross-thread global communication inside this kernel.  The ISA
// pattern "s_waitcnt lgkmcnt(0); s_barrier" keeps LDS ordering (gh, h) and
// leaves vmem in flight; the compiler still inserts its own vmcnt waits
// before gi-register USE (a full step after issue -> fully hidden).
// ---------------------------------------------------------------------------
__device__ __forceinline__ void bar_nodrain() {
    asm volatile("s_waitcnt lgkmcnt(0)" ::: "memory");
    __builtin_amdgcn_s_barrier();
    asm volatile("" ::: "memory");
}

template<int CTRL>
__device__ __forceinline__ float dpp_xor_add(float x) {
    int y = __builtin_amdgcn_mov_dpp(__float_as_int(x), CTRL, 0xF, 0xF, true);
    return x + __int_as_float(y);
}

__global__ __launch_bounds__(576) void gru_kernel(
    const float* __restrict__ gi,     // [N_][432]
    const float* __restrict__ w_hh,   // [432][144]
    const float* __restrict__ b_hh,   // [432]
    const float* __restrict__ h0,     // [128][144]
    float* __restrict__ hseq,         // [N_][144]
    float* __restrict__ hlast)        // [128][144]
{
    int b = blockIdx.x;
    int tid = threadIdx.x;
    int g = tid >> 3;       // 0..71  -> rows 6g..6g+5
    int s = tid & 7;        // k-chunk [20s, 20s+20)
    int k0 = s * 20;

    __shared__ __align__(16) float h[160];   // k-padded; [144..159] stay 0
    __shared__ float gh[G_];

    // one-time: weights into VGPRs (zero-padded past k=143)
    float w[6][20];
    #pragma unroll
    for (int r = 0; r < 6; ++r) {
        const float* wrow = &w_hh[(size_t)(6 * g + r) * D_];
        #pragma unroll
        for (int q = 0; q < 5; ++q) {
            int k = k0 + 4 * q;
            float4 t = make_float4(0.f, 0.f, 0.f, 0.f);
            if (k < D_) t = *(const float4*)&wrow[k];   // k<=140, safe
            w[r][4 * q + 0] = t.x;
            w[r][4 * q + 1] = t.y;
            w[r][4 * q + 2] = t.z;
            w[r][4 * q + 3] = t.w;
        }
    }
    float bias = (s < 6) ? b_hh[6 * g + s] : 0.f;

    if (tid < 160) h[tid] = (tid < D_) ? h0[b * D_ + tid] : 0.f;
    __syncthreads();

    // gi pipeline: registers hold step t's values at top of iteration t
    float gir = 0.f, giz = 0.f, gin = 0.f;
    if (tid < D_) {
        const float* gp = &gi[(size_t)(b * T_) * G_];
        gir = gp[tid];
        giz = gp[D_ + tid];
        gin = gp[2 * D_ + tid];
    }

    for (int t = 0; t < T_; ++t) {
        int n = b * T_ + t;

        // rotate pipeline: consume regs for step t, issue loads for t+1
        float girU = gir, gizU = giz, ginU = gin;
        if (tid < D_ && t + 1 < T_) {
            const float* gp = &gi[(size_t)(n + 1) * G_];
            gir = gp[tid];
            giz = gp[D_ + tid];
            gin = gp[2 * D_ + tid];
        }

        // h chunk: 5 conflict-free ds_read_b128
        float hv[20];
        #pragma unroll
        for (int q = 0; q < 5; ++q) {
            float4 t4 = *(const float4*)&h[k0 + 4 * q];
            hv[4 * q + 0] = t4.x;
            hv[4 * q + 1] = t4.y;
            hv[4 * q + 2] = t4.z;
            hv[4 * q + 3] = t4.w;
        }

        // 6 rows x 20 k partial dots (120 fmac, 6 independent chains)
        float a0 = 0.f, a1 = 0.f, a2 = 0.f, a3 = 0.f, a4 = 0.f, a5 = 0.f;
        #pragma unroll
        for (int kk = 0; kk < 20; ++kk) {
            float hk = hv[kk];
            a0 = fmaf(w[0][kk], hk, a0);
            a1 = fmaf(w[1][kk], hk, a1);
            a2 = fmaf(w[2][kk], hk, a2);
            a3 = fmaf(w[3][kk], hk, a3);
            a4 = fmaf(w[4][kk], hk, a4);
            a5 = fmaf(w[5][kk], hk, a5);
        }

        // reduce across the 8 k-chunk lanes: VALU DPP butterfly (no LDS)
        a0 = dpp_xor_add<0xB1>(a0); a0 = dpp_xor_add<0x4E>(a0); a0 = dpp_xor_add<0x141>(a0);
        a1 = dpp_xor_add<0xB1>(a1); a1 = dpp_xor_add<0x4E>(a1); a1 = dpp_xor_add<0x141>(a1);
        a2 = dpp_xor_add<0xB1>(a2); a2 = dpp_xor_add<0x4E>(a2); a2 = dpp_xor_add<0x141>(a2);
        a3 = dpp_xor_add<0xB1>(a3); a3 = dpp_xor_add<0x4E>(a3); a3 = dpp_xor_add<0x141>(a3);
        a4 = dpp_xor_add<0xB1>(a4); a4 = dpp_xor_add<0x4E>(a4); a4 = dpp_xor_add<0x141>(a4);
        a5 = dpp_xor_add<0xB1>(a5); a5 = dpp_xor_add<0x4E>(a5); a5 = dpp_xor_add<0x141>(a5);

        // lane s writes row 6g+s (s<6); all 8 lanes hold all 6 sums
        float myacc = a0;
        if (s == 1) myacc = a1;
        if (s == 2) myacc = a2;
        if (s == 3) myacc = a3;
        if (s == 4) myacc = a4;
        if (s == 5) myacc = a5;
        if (s < 6) gh[6 * g + s] = myacc + bias;
        bar_nodrain();            // LDS-ordered barrier, vmem stays in flight

        if (tid < D_) {
            float r = 1.f / (1.f + __expf(-(girU + gh[tid])));
            float z = 1.f / (1.f + __expf(-(gizU + gh[D_ + tid])));
            float narg = ginU + r * gh[2 * D_ + tid];
            narg = fminf(fmaxf(narg, -15.f), 15.f);
            float e2 = __expf(-2.f * narg);
            float nn = (1.f - e2) / (1.f + e2);
            float hn = (1.f - z) * nn + z * h[tid];
            hseq[(size_t)n * D_ + tid] = hn;   // store NOT drained at barrier
            h[tid] = hn;
        }
        bar_nodrain();
    }

    if (tid < D_) hlast[b * D_ + tid] = h[tid];
}

// ---------------------------------------------------------------------------
extern "C" void kernel_launch(void* const* d_in, const int* in_sizes, int n_in,
                              void* d_out, int out_size, void* d_ws, size_t ws_size,
                              hipStream_t stream)
{
    const int*   x         = (const int*)d_in[0];
    // d_in[1] = lengths (unused by the reference computation)
    const float* hidden    = (const float*)d_in[2];
    const float* encode_w  = (const float*)d_in[3];
    const float* wchange_w = (const float*)d_in[4];
    const float* w_ih      = (const float*)d_in[5];
    const float* w_hh      = (const float*)d_in[6];
    const float* b_ih      = (const float*)d_in[7];
    const float* b_hh      = (const float*)d_in[8];
    const float* fc_w      = (const float*)d_in[9];
    const float* fc_b      = (const float*)d_in[10];

    float* out = (float*)d_out;              // [N_][128] then [128][144]
    float* ws  = (float*)d_ws;
    float* seq  = ws;                        //   921600 floats
    float* gi   = ws + 921600;               //  2764800 floats
    float* hseq = ws + 921600 + 2764800;     //   921600 floats  (18.4 MB total)

    // K1: embedding (parallel gather v2)
    embed_kernel<<<N_, 256, 0, stream>>>(x, encode_w, wchange_w, seq);

    // K2: gi = seq @ w_ih^T + b_ih   (M=6400, N=432) — 128x128/8x8 kernel
    gemm128_bias_kernel<<<dim3(N_ / 128, (G_ + 127) / 128), 256, 0, stream>>>(
        seq, w_ih, b_ih, gi, N_, G_);

    // K3: GRU over T=50 (v7 = v6 + no-drain barriers)
    gru_kernel<<<B_, 576, 0, stream>>>(gi, w_hh, b_hh, hidden, hseq,
                                       out + (size_t)N_ * E_);

    // K4: dynamic_user = hseq @ fc_w^T + fc_b   (M=6400, N=128) — 64x64 tile
    gemm_bias_kernel<<<dim3(N_ / 64, E_ / 64), 256, 0, stream>>>(
        hseq, fc_w, fc_b, out, N_, E_);
}

// Round 5
// 187.974 us; speedup vs baseline: 1.0618x; 1.0618x over previous
//
#include <hip/hip_runtime.h>
#include <math.h>

#define B_   128
#define T_   50
#define MI_  32
#define E_   128
#define EW_  16
#define D_   144
#define G_   432        // 3*D
#define N_   (B_*T_)    // 6400

// ---------------------------------------------------------------------------
// K1: basket embedding v2 — parallel gather (unchanged, known good).
// ---------------------------------------------------------------------------
__global__ __launch_bounds__(256) void embed_kernel(
    const int* __restrict__ x,            // [N_][33]
    const float* __restrict__ encode_w,   // [100000][128]  (row 0 == 0)
    const float* __restrict__ wchange_w,  // [2][16]
    float* __restrict__ seq)              // [N_][144]
{
    int n = blockIdx.x;
    int tid = threadIdx.x;
    int i = tid >> 3;        // item 0..31
    int j = tid & 7;         // col chunk [16j, 16j+16)

    __shared__ int xi[33];
    __shared__ __align__(16) float part[32 * 132];  // stride 132 words
    __shared__ float cntf[32];

    if (tid < 33) xi[tid] = x[n * 33 + tid];
    __syncthreads();

    int it = xi[i];
    const float* row = &encode_w[(size_t)it * E_];
    float4 v0 = *(const float4*)&row[16 * j + 0];
    float4 v1 = *(const float4*)&row[16 * j + 4];
    float4 v2 = *(const float4*)&row[16 * j + 8];
    float4 v3 = *(const float4*)&row[16 * j + 12];

    float* p = &part[i * 132 + 16 * j];
    *(float4*)&p[0]  = v0;
    *(float4*)&p[4]  = v1;
    *(float4*)&p[8]  = v2;
    *(float4*)&p[12] = v3;
    if (j == 0) cntf[i] = (it != 0) ? 1.f : 0.f;
    __syncthreads();

    if (tid < E_) {
        int c = tid;
        float s = 0.f, cn = 0.f;
        #pragma unroll
        for (int k = 0; k < 32; ++k) {
            s  += part[k * 132 + c];   // 2-way bank aliasing: free
            cn += cntf[k];             // broadcast: free
        }
        seq[n * D_ + c] = s / fmaxf(cn, 1.f);
    } else if (tid < E_ + EW_) {
        int c = tid - E_;
        seq[n * D_ + E_ + c] = wchange_w[xi[32] * EW_ + c];
    }
}

// ---------------------------------------------------------------------------
// K2/K4: C[M][N] = A[M][144] * Bw[N][144]^T + bias[N].  64x64 tile, 4x4 acc
// (the round-4 128x128 experiment regressed: 200 wgs <1 block/CU, no
// co-resident latency cover — tile changes must preserve grid density).
// v2: DOUBLE-BUFFERED LDS + T14 async-stage: next tile's global loads are
// issued BEFORE the compute loop (latency hides under 48-k FMA), LDS writes
// land in the alternate buffer after compute, ONE barrier per k-iter
// (4 barriers/block vs 6, no exposed stage latency).
// ---------------------------------------------------------------------------
#define GK   144
#define GBK  48
#define GPAD 68

__global__ __launch_bounds__(256) void gemm_dbuf_bias_kernel(
    const float* __restrict__ A,
    const float* __restrict__ Bw,
    const float* __restrict__ bias,
    float* __restrict__ C,
    int M, int N)
{
    __shared__ float As[2][GBK * GPAD];
    __shared__ float Bs[2][GBK * GPAD];

    int tid = threadIdx.x;
    int row0 = blockIdx.x * 64;
    int col0 = blockIdx.y * 64;
    int tx = tid & 15;        // col group
    int ty = tid >> 4;        // row group

    int sr   = tid >> 2;      // staged row 0..63
    int skq0 = tid & 3;
    int nrow = col0 + sr;
    bool bok = (nrow < N);

    const float4 z4 = make_float4(0.f, 0.f, 0.f, 0.f);
    float4 ra[3], rb[3];

    // prologue: tile 0 -> regs -> LDS buf 0
    #pragma unroll
    for (int i = 0; i < 3; ++i) {
        int kq = skq0 + i * 4;
        ra[i] = *(const float4*)&A[(size_t)(row0 + sr) * GK + kq * 4];
        rb[i] = bok ? *(const float4*)&Bw[(size_t)nrow * GK + kq * 4] : z4;
    }
    #pragma unroll
    for (int i = 0; i < 3; ++i) {
        int kq = skq0 + i * 4;
        As[0][(kq * 4 + 0) * GPAD + sr] = ra[i].x;
        As[0][(kq * 4 + 1) * GPAD + sr] = ra[i].y;
        As[0][(kq * 4 + 2) * GPAD + sr] = ra[i].z;
        As[0][(kq * 4 + 3) * GPAD + sr] = ra[i].w;
        Bs[0][(kq * 4 + 0) * GPAD + sr] = rb[i].x;
        Bs[0][(kq * 4 + 1) * GPAD + sr] = rb[i].y;
        Bs[0][(kq * 4 + 2) * GPAD + sr] = rb[i].z;
        Bs[0][(kq * 4 + 3) * GPAD + sr] = rb[i].w;
    }
    __syncthreads();

    float acc[4][4] = {};
    int cur = 0;

    for (int k0 = 0; k0 < GK; k0 += GBK) {
        bool more = (k0 + GBK < GK);
        // T14 issue-early: next tile's global loads in flight during compute
        if (more) {
            #pragma unroll
            for (int i = 0; i < 3; ++i) {
                int kq = skq0 + i * 4;
                ra[i] = *(const float4*)&A[(size_t)(row0 + sr) * GK + k0 + GBK + kq * 4];
                rb[i] = bok ? *(const float4*)&Bw[(size_t)nrow * GK + k0 + GBK + kq * 4] : z4;
            }
        }

        #pragma unroll 4
        for (int k = 0; k < GBK; ++k) {
            float4 a4 = *(const float4*)&As[cur][k * GPAD + ty * 4];
            float4 b4 = *(const float4*)&Bs[cur][k * GPAD + tx * 4];
            float av[4] = {a4.x, a4.y, a4.z, a4.w};
            float bv[4] = {b4.x, b4.y, b4.z, b4.w};
            #pragma unroll
            for (int i = 0; i < 4; ++i)
                #pragma unroll
                for (int j = 0; j < 4; ++j)
                    acc[i][j] = fmaf(av[i], bv[j], acc[i][j]);
        }

        // write-late into the ALTERNATE buffer (nobody reads it this iter)
        if (more) {
            #pragma unroll
            for (int i = 0; i < 3; ++i) {
                int kq = skq0 + i * 4;
                As[cur ^ 1][(kq * 4 + 0) * GPAD + sr] = ra[i].x;
                As[cur ^ 1][(kq * 4 + 1) * GPAD + sr] = ra[i].y;
                As[cur ^ 1][(kq * 4 + 2) * GPAD + sr] = ra[i].z;
                As[cur ^ 1][(kq * 4 + 3) * GPAD + sr] = ra[i].w;
                Bs[cur ^ 1][(kq * 4 + 0) * GPAD + sr] = rb[i].x;
                Bs[cur ^ 1][(kq * 4 + 1) * GPAD + sr] = rb[i].y;
                Bs[cur ^ 1][(kq * 4 + 2) * GPAD + sr] = rb[i].z;
                Bs[cur ^ 1][(kq * 4 + 3) * GPAD + sr] = rb[i].w;
            }
            __syncthreads();   // block-uniform: 'more' depends only on k0
            cur ^= 1;
        }
    }

    int c = col0 + tx * 4;
    if (c < N) {
        float4 bb = *(const float4*)&bias[c];
        #pragma unroll
        for (int i = 0; i < 4; ++i) {
            int r = row0 + ty * 4 + i;
            float4 o;
            o.x = acc[i][0] + bb.x;
            o.y = acc[i][1] + bb.y;
            o.z = acc[i][2] + bb.z;
            o.w = acc[i][3] + bb.w;
            *(float4*)&C[(size_t)r * N + c] = o;
        }
    }
}

// ---------------------------------------------------------------------------
// K3: GRU v6 (best measured: 52.9us) — v3 structure + 1-step-ahead gi
// pipeline.  Round-4 learned: bar_nodrain (raw s_barrier, no vmcnt drain)
// is NULL (+0.4us) -> plain __syncthreads kept.  v4/v5 lessons: elementwise
// stays dense in tid<144; no extra resident weight arrays (register cap).
// ---------------------------------------------------------------------------
template<int CTRL>
__device__ __forceinline__ float dpp_xor_add(float x) {
    int y = __builtin_amdgcn_mov_dpp(__float_as_int(x), CTRL, 0xF, 0xF, true);
    return x + __int_as_float(y);
}

__global__ __launch_bounds__(576) void gru_kernel(
    const float* __restrict__ gi,     // [N_][432]
    const float* __restrict__ w_hh,   // [432][144]
    const float* __restrict__ b_hh,   // [432]
    const float* __restrict__ h0,     // [128][144]
    float* __restrict__ hseq,         // [N_][144]
    float* __restrict__ hlast)        // [128][144]
{
    int b = blockIdx.x;
    int tid = threadIdx.x;
    int g = tid >> 3;       // 0..71  -> rows 6g..6g+5
    int s = tid & 7;        // k-chunk [20s, 20s+20)
    int k0 = s * 20;

    __shared__ __align__(16) float h[160];   // k-padded; [144..159] stay 0
    __shared__ float gh[G_];

    // one-time: weights into VGPRs (zero-padded past k=143)
    float w[6][20];
    #pragma unroll
    for (int r = 0; r < 6; ++r) {
        const float* wrow = &w_hh[(size_t)(6 * g + r) * D_];
        #pragma unroll
        for (int q = 0; q < 5; ++q) {
            int k = k0 + 4 * q;
            float4 t = make_float4(0.f, 0.f, 0.f, 0.f);
            if (k < D_) t = *(const float4*)&wrow[k];   // k<=140, safe
            w[r][4 * q + 0] = t.x;
            w[r][4 * q + 1] = t.y;
            w[r][4 * q + 2] = t.z;
            w[r][4 * q + 3] = t.w;
        }
    }
    float bias = (s < 6) ? b_hh[6 * g + s] : 0.f;

    if (tid < 160) h[tid] = (tid < D_) ? h0[b * D_ + tid] : 0.f;
    __syncthreads();

    // gi pipeline: registers hold step t's values at top of iteration t
    float gir = 0.f, giz = 0.f, gin = 0.f;
    if (tid < D_) {
        const float* gp = &gi[(size_t)(b * T_) * G_];
        gir = gp[tid];
        giz = gp[D_ + tid];
        gin = gp[2 * D_ + tid];
    }

    for (int t = 0; t < T_; ++t) {
        int n = b * T_ + t;

        // rotate pipeline: consume regs for step t, issue loads for t+1
        float girU = gir, gizU = giz, ginU = gin;
        if (tid < D_ && t + 1 < T_) {
            const float* gp = &gi[(size_t)(n + 1) * G_];
            gir = gp[tid];
            giz = gp[D_ + tid];
            gin = gp[2 * D_ + tid];
        }

        // h chunk: 5 conflict-free ds_read_b128
        float hv[20];
        #pragma unroll
        for (int q = 0; q < 5; ++q) {
            float4 t4 = *(const float4*)&h[k0 + 4 * q];
            hv[4 * q + 0] = t4.x;
            hv[4 * q + 1] = t4.y;
            hv[4 * q + 2] = t4.z;
            hv[4 * q + 3] = t4.w;
        }

        // 6 rows x 20 k partial dots (120 fmac, 6 independent chains)
        float a0 = 0.f, a1 = 0.f, a2 = 0.f, a3 = 0.f, a4 = 0.f, a5 = 0.f;
        #pragma unroll
        for (int kk = 0; kk < 20; ++kk) {
            float hk = hv[kk];
            a0 = fmaf(w[0][kk], hk, a0);
            a1 = fmaf(w[1][kk], hk, a1);
            a2 = fmaf(w[2][kk], hk, a2);
            a3 = fmaf(w[3][kk], hk, a3);
            a4 = fmaf(w[4][kk], hk, a4);
            a5 = fmaf(w[5][kk], hk, a5);
        }

        // reduce across the 8 k-chunk lanes: VALU DPP butterfly (no LDS)
        a0 = dpp_xor_add<0xB1>(a0); a0 = dpp_xor_add<0x4E>(a0); a0 = dpp_xor_add<0x141>(a0);
        a1 = dpp_xor_add<0xB1>(a1); a1 = dpp_xor_add<0x4E>(a1); a1 = dpp_xor_add<0x141>(a1);
        a2 = dpp_xor_add<0xB1>(a2); a2 = dpp_xor_add<0x4E>(a2); a2 = dpp_xor_add<0x141>(a2);
        a3 = dpp_xor_add<0xB1>(a3); a3 = dpp_xor_add<0x4E>(a3); a3 = dpp_xor_add<0x141>(a3);
        a4 = dpp_xor_add<0xB1>(a4); a4 = dpp_xor_add<0x4E>(a4); a4 = dpp_xor_add<0x141>(a4);
        a5 = dpp_xor_add<0xB1>(a5); a5 = dpp_xor_add<0x4E>(a5); a5 = dpp_xor_add<0x141>(a5);

        // lane s writes row 6g+s (s<6); all 8 lanes hold all 6 sums
        float myacc = a0;
        if (s == 1) myacc = a1;
        if (s == 2) myacc = a2;
        if (s == 3) myacc = a3;
        if (s == 4) myacc = a4;
        if (s == 5) myacc = a5;
        if (s < 6) gh[6 * g + s] = myacc + bias;
        __syncthreads();

        if (tid < D_) {
            float r = 1.f / (1.f + __expf(-(girU + gh[tid])));
            float z = 1.f / (1.f + __expf(-(gizU + gh[D_ + tid])));
            float narg = ginU + r * gh[2 * D_ + tid];
            narg = fminf(fmaxf(narg, -15.f), 15.f);
            float e2 = __expf(-2.f * narg);
            float nn = (1.f - e2) / (1.f + e2);
            float hn = (1.f - z) * nn + z * h[tid];
            hseq[(size_t)n * D_ + tid] = hn;
            h[tid] = hn;
        }
        __syncthreads();
    }

    if (tid < D_) hlast[b * D_ + tid] = h[tid];
}

// ---------------------------------------------------------------------------
extern "C" void kernel_launch(void* const* d_in, const int* in_sizes, int n_in,
                              void* d_out, int out_size, void* d_ws, size_t ws_size,
                              hipStream_t stream)
{
    const int*   x         = (const int*)d_in[0];
    // d_in[1] = lengths (unused by the reference computation)
    const float* hidden    = (const float*)d_in[2];
    const float* encode_w  = (const float*)d_in[3];
    const float* wchange_w = (const float*)d_in[4];
    const float* w_ih      = (const float*)d_in[5];
    const float* w_hh      = (const float*)d_in[6];
    const float* b_ih      = (const float*)d_in[7];
    const float* b_hh      = (const float*)d_in[8];
    const float* fc_w      = (const float*)d_in[9];
    const float* fc_b      = (const float*)d_in[10];

    float* out = (float*)d_out;              // [N_][128] then [128][144]
    float* ws  = (float*)d_ws;
    float* seq  = ws;                        //   921600 floats
    float* gi   = ws + 921600;               //  2764800 floats
    float* hseq = ws + 921600 + 2764800;     //   921600 floats  (18.4 MB total)

    // K1: embedding (parallel gather v2)
    embed_kernel<<<N_, 256, 0, stream>>>(x, encode_w, wchange_w, seq);

    // K2: gi = seq @ w_ih^T + b_ih   (M=6400, N=432) — 64x64 dbuf kernel
    gemm_dbuf_bias_kernel<<<dim3(N_ / 64, (G_ + 63) / 64), 256, 0, stream>>>(
        seq, w_ih, b_ih, gi, N_, G_);

    // K3: GRU over T=50 (v6: best measured)
    gru_kernel<<<B_, 576, 0, stream>>>(gi, w_hh, b_hh, hidden, hseq,
                                       out + (size_t)N_ * E_);

    // K4: dynamic_user = hseq @ fc_w^T + fc_b   (M=6400, N=128) — dbuf kernel
    gemm_dbuf_bias_kernel<<<dim3(N_ / 64, E_ / 64), 256, 0, stream>>>(
        hseq, fc_w, fc_b, out, N_, E_);
}